// Round 4
// baseline (147.443 us; speedup 1.0000x reference)
//
#include <hip/hip_runtime.h>
#include <cstdint>
#include <cstddef>

// ---------------------------------------------------------------------------
// Threefry-2x32, 20 rounds, key = threefry_seed(42) = (0, 42)  (JAX-exact)
// ---------------------------------------------------------------------------
__device__ __forceinline__ uint32_t rotl32(uint32_t v, int d) {
  return (v << d) | (v >> (32 - d));
}

__device__ __forceinline__ void threefry2x32_seed42(uint32_t c0, uint32_t c1,
                                                    uint32_t& o0, uint32_t& o1) {
  const uint32_t ks0 = 0u;
  const uint32_t ks1 = 42u;
  const uint32_t ks2 = ks0 ^ ks1 ^ 0x1BD11BDAu;
  uint32_t x0 = c0 + ks0;
  uint32_t x1 = c1 + ks1;
#define TF_R(r) { x0 += x1; x1 = rotl32(x1, (r)); x1 ^= x0; }
  TF_R(13) TF_R(15) TF_R(26) TF_R(6)
  x0 += ks1; x1 += ks2 + 1u;
  TF_R(17) TF_R(29) TF_R(16) TF_R(24)
  x0 += ks2; x1 += ks0 + 2u;
  TF_R(13) TF_R(15) TF_R(26) TF_R(6)
  x0 += ks0; x1 += ks1 + 3u;
  TF_R(17) TF_R(29) TF_R(16) TF_R(24)
  x0 += ks1; x1 += ks2 + 4u;
  TF_R(13) TF_R(15) TF_R(26) TF_R(6)
  x0 += ks2; x1 += ks0 + 5u;
#undef TF_R
  o0 = x0; o1 = x1;
}

// JAX partitionable stream (default >= 0.5): counter = (0, f), bits = o0^o1.
__device__ __forceinline__ uint32_t jax_random_bits32(uint32_t f) {
  uint32_t o0, o1;
  threefry2x32_seed42(0u, f, o0, o1);
  return o0 ^ o1;
}

// Gumbel g = -log(-log(u)), fp32-rounded at each step (matches XLA fp32 path
// to ~1 ulp; u pipeline is bit-exact).
__device__ __forceinline__ float gumbel_f(uint32_t f) {
  const uint32_t bits = jax_random_bits32(f);
  const float base = __uint_as_float((bits >> 9) | 0x3F800000u) - 1.0f;
  const float u = fmaxf(1e-10f, __fadd_rn(base, 1e-10f));
  const float w = (float)(-log((double)u));
  const float g = (float)(-log((double)w));
  return g;
}

// ---------------------------------------------------------------------------
// int64-vs-int32 edge_index detection (indices < 50000 -> int64 high words 0).
// ---------------------------------------------------------------------------
__global__ void detect_idx_dtype(const unsigned long long* __restrict__ buf,
                                 int n64, int* __restrict__ flag) {
  __shared__ int cnt;
  if (threadIdx.x == 0) cnt = 0;
  __syncthreads();
  if ((int)threadIdx.x < n64) {
    if ((buf[threadIdx.x] >> 32) != 0ull) atomicAdd(&cnt, 1);
  }
  __syncthreads();
  if (threadIdx.x == 0) *flag = (cnt * 2 < n64) ? 1 : 0;  // 1 => int64
}

// ---------------------------------------------------------------------------
// One thread per edge, latency-optimized:
//  - double-buffered register chunks: 2 x (8+8) float4 loads in flight
//  - Gumbel/Threefry VALU work issued while first 32 loads are in flight
//  - strict sequential fp32 add chain (XLA:CPU order), no FMA contraction
// ---------------------------------------------------------------------------
__global__ __launch_bounds__(256) void ipd_mlp(
    const float* __restrict__ z1, const float* __restrict__ z2,
    const void* __restrict__ eidx, const int* __restrict__ flag64,
    float* __restrict__ out, int E) {
  const long long e = (long long)blockIdx.x * blockDim.x + threadIdx.x;
  if (e >= E) return;
  const bool is64 = (*flag64 != 0);

  long long i0, i1;
  if (is64) {
    const long long* p = (const long long*)eidx;
    i0 = p[e]; i1 = p[E + e];
  } else {
    const int* p = (const int*)eidx;
    i0 = p[e]; i1 = p[E + e];
  }

  const float4* __restrict__ r0 = (const float4*)(z1 + (size_t)i0 * 128);
  const float4* __restrict__ r1 = (const float4*)(z1 + (size_t)i1 * 128);

  float4 A0[8], B0[8], A1[8], B1[8];

  // issue chunk 0 and chunk 1 loads (32 float4 in flight) + z2 loads
#pragma unroll
  for (int i = 0; i < 8; ++i) { A0[i] = r0[i];     B0[i] = r1[i];     }
#pragma unroll
  for (int i = 0; i < 8; ++i) { A1[i] = r0[8 + i]; B1[i] = r1[8 + i]; }
  const float z2a = z2[(size_t)i0 * 2];
  const float z2b = z2[(size_t)i1 * 2];

  // hide gather latency under the Threefry/Gumbel VALU work
  const float g0 = gumbel_f(2u * (uint32_t)e);
  const float g1 = gumbel_f(2u * (uint32_t)e + 1u);

  float acc = 0.0f;
#define SUMC(SA, SB)                                            \
  _Pragma("unroll")                                             \
  for (int i = 0; i < 8; ++i) {                                 \
    acc = __fadd_rn(acc, __fmul_rn(SA[i].x, SB[i].x));          \
    acc = __fadd_rn(acc, __fmul_rn(SA[i].y, SB[i].y));          \
    acc = __fadd_rn(acc, __fmul_rn(SA[i].z, SB[i].z));          \
    acc = __fadd_rn(acc, __fmul_rn(SA[i].w, SB[i].w));          \
  }

  SUMC(A0, B0)                               // consume chunk 0
#pragma unroll
  for (int i = 0; i < 8; ++i) { A0[i] = r0[16 + i]; B0[i] = r1[16 + i]; }
  SUMC(A1, B1)                               // consume chunk 1
#pragma unroll
  for (int i = 0; i < 8; ++i) { A1[i] = r0[24 + i]; B1[i] = r1[24 + i]; }
  SUMC(A0, B0)                               // consume chunk 2
  SUMC(A1, B1)                               // consume chunk 3
#undef SUMC

  const float s0 = __fadd_rn(acc, g0);       // (vf + g0) / tau, tau == 1
  const float d  = __fsub_rn(s0, g1);
  bool a = (d >= 0.0f);
  if (!a) {
    a = ((float)exp((double)d) >= 1.0f);     // softmax tie -> argmax 0 -> a=1
  }

  const float vn = __fadd_rn(z2a, z2b);
  const float sf = 1.0f / (1.0f + expf(-acc));
  const float sn = 1.0f / (1.0f + expf(-vn));
  out[e] = a ? sf : sn;
}

// ---------------------------------------------------------------------------
extern "C" void kernel_launch(void* const* d_in, const int* in_sizes, int n_in,
                              void* d_out, int out_size, void* d_ws, size_t ws_size,
                              hipStream_t stream) {
  const float* z1  = (const float*)d_in[0];
  const float* z2  = (const float*)d_in[1];
  const void* eidx = d_in[2];
  // d_in[3] = temp (==1); tau > 0 does not change the hard argmax.

  const int E = in_sizes[2] / 2;

  int* flag = (int*)d_ws;
  int n64 = E < 256 ? E : 256;
  hipLaunchKernelGGL(detect_idx_dtype, dim3(1), dim3(256), 0, stream,
                     (const unsigned long long*)eidx, n64, flag);

  const int threads = 256;
  const int blocks = (E + threads - 1) / threads;
  hipLaunchKernelGGL(ipd_mlp, dim3(blocks), dim3(threads), 0, stream,
                     z1, z2, eidx, flag, (float*)d_out, E);
}